// Round 5
// baseline (950.923 us; speedup 1.0000x reference)
//
#include <hip/hip_runtime.h>

#define T_ 4
#define B_ 64
#define D_ 512
#define V_ 256

// ---- workspace byte offsets ----
#define XSH   0ull             // x^T split hi (t*64+b, v, d) bf16, 67.1 MB
#define XSM   67108864ull
#define XSL   134217728ull
#define OUTBT 201326592ull     // gate*k spikes, (t*64+b, v, d) bf16 {0,1}, 67.1 MB
#define WT    268435456ull     // frag-tiled W splits: (mat*3+s) arrays of 512KB
#define BNOF  273154048ull     // 6x512 floats

typedef unsigned short u16;
typedef __attribute__((ext_vector_type(8))) __bf16 bf16x8;
typedef __attribute__((ext_vector_type(4))) float f32x4;
typedef __attribute__((ext_vector_type(8))) unsigned short u16x8;
typedef __attribute__((ext_vector_type(4))) unsigned short u16x4;

__device__ __forceinline__ u16 f2bf(float f) {
    unsigned u = __float_as_uint(f);
    return (u16)((u + 0x7FFFu + ((u >> 16) & 1u)) >> 16);
}
__device__ __forceinline__ float bf2f(u16 h) {
    return __uint_as_float(((unsigned)h) << 16);
}

// async global->LDS, 16B/lane; LDS dest = wave-uniform base + lane*16
__device__ __forceinline__ void gld_lds16(const void* g, void* l) {
    __builtin_amdgcn_global_load_lds(
        (const __attribute__((address_space(1))) unsigned int*)(unsigned long long)g,
        (__attribute__((address_space(3))) unsigned int*)(unsigned long long)l,
        16, 0, 0);
}

// ---------------------------------------------------------------------------
// prep: W splits in FRAG-LINEAR layout + BN constants.
// Array (mat,s): idx = ((head*16+it)*8+ip)*512 + lane*8 + e  holds
//   W[head*128 + ip*16 + (lane&15)][it*32 + (lane>>4)*8 + e]  (split s)
// ---------------------------------------------------------------------------
__global__ __launch_bounds__(256) void k_prep2(
    const float* __restrict__ Wq, const float* __restrict__ Wk, const float* __restrict__ Wp,
    const float* __restrict__ qg, const float* __restrict__ qb,
    const float* __restrict__ qm, const float* __restrict__ qv,
    const float* __restrict__ kg, const float* __restrict__ kb,
    const float* __restrict__ km, const float* __restrict__ kv,
    const float* __restrict__ pg, const float* __restrict__ pb,
    const float* __restrict__ pm, const float* __restrict__ pv,
    char* __restrict__ ws)
{
    const int g = blockIdx.x * 256 + threadIdx.x;   // [0, 98304)
    const int mat = g >> 15;
    const int r = g & 32767;
    const int lane = r & 63;
    const int q = r >> 6;            // 0..511 = (head*16+it)*8+ip
    const int ip = q & 7;
    const int q2 = q >> 3;
    const int it = q2 & 15;
    const int head = q2 >> 4;
    const int row = head * 128 + ip * 16 + (lane & 15);
    const int kcol = it * 32 + (lane >> 4) * 8;
    const float* W = (mat == 0) ? Wq : (mat == 1 ? Wk : Wp);

    u16x8 h8, m8, l8;
#pragma unroll
    for (int e = 0; e < 8; ++e) {
        const float f = W[row * 512 + kcol + e];
        const u16 h = f2bf(f);          const float fh = bf2f(h);
        const u16 m = f2bf(f - fh);     const float fm = bf2f(m);
        const u16 l = f2bf(f - fh - fm);
        h8[e] = h; m8[e] = m; l8[e] = l;
    }
    u16* wt = (u16*)(ws + WT);
    const size_t o = (size_t)r * 8;
    *(u16x8*)(wt + (size_t)(mat * 3 + 0) * 262144 + o) = h8;
    *(u16x8*)(wt + (size_t)(mat * 3 + 1) * 262144 + o) = m8;
    *(u16x8*)(wt + (size_t)(mat * 3 + 2) * 262144 + o) = l8;

    if (g < 512) {
        float* bn = (float*)(ws + BNOF);
        float iv;
        iv = qg[g] * (1.0f / sqrtf(qv[g] + 1e-5f)); bn[g]        = iv; bn[512  + g] = qb[g] - qm[g] * iv;
        iv = kg[g] * (1.0f / sqrtf(kv[g] + 1e-5f)); bn[1024 + g] = iv; bn[1536 + g] = kb[g] - km[g] * iv;
        iv = pg[g] * (1.0f / sqrtf(pv[g] + 1e-5f)); bn[2048 + g] = iv; bn[2560 + g] = pb[g] - pm[g] * iv;
    }
}

// ---------------------------------------------------------------------------
// split_x: x (t,b,d,v) fp32 -> transposed 3-way bf16 splits (t*64+b, v, d)
// ---------------------------------------------------------------------------
__global__ __launch_bounds__(256) void k_split_x(
    const float* __restrict__ x,
    u16* __restrict__ xh, u16* __restrict__ xm, u16* __restrict__ xl)
{
    __shared__ float tile[64][65];
    const int bt = blockIdx.z;
    const int d0 = blockIdx.y * 64;
    const int v0 = blockIdx.x * 64;
    const int c  = threadIdx.x & 63;
    const int r4 = threadIdx.x >> 6;

    const float* src = x + ((size_t)bt * D_ + d0) * V_ + v0;
#pragma unroll
    for (int i = 0; i < 16; ++i) {
        const int row = i * 4 + r4;
        tile[row][c] = src[(size_t)row * V_ + c];
    }
    __syncthreads();
#pragma unroll
    for (int i = 0; i < 16; ++i) {
        const int vr = i * 4 + r4;
        const float f = tile[c][vr];
        const u16 h = f2bf(f);          const float fh = bf2f(h);
        const u16 m = f2bf(f - fh);     const float fm = bf2f(m);
        const u16 l = f2bf(f - fh - fm);
        const size_t o = ((size_t)bt * V_ + v0 + vr) * D_ + d0 + c;
        xh[o] = h; xm[o] = m; xl[o] = l;
    }
}

// ---------------------------------------------------------------------------
// Fused q+k: per block = (b, head, v-tile 128), both GEMM phases over all 4 t.
// BK=64 per barrier (8 K-iters): 2x MFMA per barrier drain vs BK=32.
// ---------------------------------------------------------------------------
__global__ __launch_bounds__(256, 2) void k_qk_fused(char* __restrict__ ws)
{
    __shared__ u16 stg[24576];       // B staging (3 splits x 16 chunks x 512) = 48KB
                                     // union: out tile (128x136 u16 = 34.8KB)
    __shared__ float qs[256];        // partial head sums
    __shared__ float gatef[512];     // [t][col]

    const int tid  = threadIdx.x;
    const int lane = tid & 63;
    const int wave = tid >> 6;
    const int wr = wave >> 1, wc = wave & 1;
    const int quad = lane >> 4;
    const int l15  = lane & 15;

    const unsigned bid  = blockIdx.x;
    const unsigned rr   = bid >> 3;
    const unsigned head = rr & 3;
    const unsigned unit = (bid & 7) + 8u * (rr >> 2);   // same-XCD groups share (b,vt)
    const unsigned b    = unit >> 1;
    const unsigned vt   = unit & 1;
    const unsigned v0   = vt * 128u;
    const unsigned o0h  = head * 128u;

    // B per-lane byte base (t=0, chunk f=0, it=0)
    const unsigned rbase = (b * 256u + v0 + (unsigned)l15) * 1024u + (unsigned)(lane >> 4) * 16u;
    const unsigned xsb[3] = {(unsigned)XSH, (unsigned)XSM, (unsigned)XSL};

    const int PA[6] = {0, 0, 1, 1, 0, 2};
    const int PB[6] = {0, 1, 0, 1, 2, 0};

    float gstate = 0.f;   // gate LIF state (used by tid<128)

    for (int ph = 0; ph < 2; ++ph) {
        unsigned ab[3];
#pragma unroll
        for (int s = 0; s < 3; ++s)
            ab[s] = (unsigned)WT + ((unsigned)ph * 3u + (unsigned)s) * 524288u
                  + head * 131072u + (unsigned)wr * 4096u + (unsigned)lane * 16u;
        const float* bn = (const float*)(ws + BNOF + (size_t)ph * 4096);

        f32x4 st[4][4];   // LIF membrane state
#pragma unroll
        for (int i = 0; i < 4; ++i)
#pragma unroll
            for (int j = 0; j < 4; ++j) st[i][j] = (f32x4){0.f, 0.f, 0.f, 0.f};

        for (int t = 0; t < 4; ++t) {
            f32x4 acc[4][4];
#pragma unroll
            for (int i = 0; i < 4; ++i)
#pragma unroll
                for (int j = 0; j < 4; ++j) acc[i][j] = (f32x4){0.f, 0.f, 0.f, 0.f};

            const unsigned tb = (unsigned)t * 16777216u + rbase;

            for (int it2 = 0; it2 < 8; ++it2) {
                const unsigned ko = (unsigned)it2 * 128u;   // 64 k-elems * 2B
                // stage B: 48 chunks of 1KB, 12 per wave
#pragma unroll
                for (int u = 0; u < 12; ++u) {
                    const int fg = wave * 12 + u;           // 0..47
                    const int ai = fg >> 4;                 // split
                    const int rem = fg & 15;
                    const int kh = rem >> 3, f = rem & 7;
                    gld_lds16(ws + (size_t)(xsb[ai] + tb + (unsigned)f * 16384u
                                            + ko + (unsigned)kh * 64u),
                              stg + (size_t)(ai * 16 + kh * 8 + f) * 512);
                }
                __syncthreads();

#pragma unroll
                for (int kh = 0; kh < 2; ++kh) {
                    bf16x8 bfr[3][4];
#pragma unroll
                    for (int s = 0; s < 3; ++s)
#pragma unroll
                        for (int j = 0; j < 4; ++j)
                            bfr[s][j] = *(const bf16x8*)(stg
                                + (size_t)(s * 16 + kh * 8 + wc * 4 + j) * 512 + lane * 8);
#pragma unroll
                    for (int i = 0; i < 4; ++i) {
                        bf16x8 afr[3];
#pragma unroll
                        for (int s = 0; s < 3; ++s)
                            afr[s] = *(const bf16x8*)(ws + (size_t)(ab[s]
                                      + (unsigned)it2 * 16384u + (unsigned)kh * 8192u
                                      + (unsigned)i * 1024u));
#pragma unroll
                        for (int p = 0; p < 6; ++p)
#pragma unroll
                            for (int j = 0; j < 4; ++j)
                                acc[i][j] = __builtin_amdgcn_mfma_f32_16x16x32_bf16(
                                    afr[PA[p]], bfr[PB[p]][j], acc[i][j], 0, 0, 0);
                    }
                }
                __syncthreads();
            }

            if (ph == 0) {
                // ---- phase Q epilogue: BN + LIF + per-column spike sums ----
                float qp[4] = {0.f, 0.f, 0.f, 0.f};
#pragma unroll
                for (int i = 0; i < 4; ++i) {
                    const int ob = (int)o0h + wr * 64 + i * 16 + quad * 4;
                    const f32x4 inv = *(const f32x4*)(bn + ob);
                    const f32x4 add = *(const f32x4*)(bn + 512 + ob);
#pragma unroll
                    for (int j = 0; j < 4; ++j)
#pragma unroll
                        for (int r = 0; r < 4; ++r) {
                            const float y = acc[i][j][r] * inv[r] + add[r];
                            float v = (st[i][j][r] + y) * 0.5f;
                            const float s = (v >= 1.0f) ? 1.f : 0.f;
                            st[i][j][r] = (v >= 1.0f) ? 0.f : v;
                            qp[j] += s;
                        }
                }
#pragma unroll
                for (int j = 0; j < 4; ++j) {
                    qp[j] += __shfl_xor(qp[j], 16, 64);
                    qp[j] += __shfl_xor(qp[j], 32, 64);
                }
                if (quad == 0) {
#pragma unroll
                    for (int j = 0; j < 4; ++j)
                        qs[wr * 128 + wc * 64 + j * 16 + l15] = qp[j];
                }
                __syncthreads();
                if (tid < 128) {
                    const float qsum = qs[tid] + qs[128 + tid];
                    gstate = (gstate + qsum) * 0.5f;
                    const float gt = (gstate >= 0.5f) ? 1.f : 0.f;
                    gstate = (gstate >= 0.5f) ? 0.f : gstate;
                    gatef[t * 128 + tid] = gt;
                }
                __syncthreads();
            } else {
                // ---- phase K epilogue: BN + LIF + gate -> out^T tile ----
#pragma unroll
                for (int i = 0; i < 4; ++i) {
                    const int ob = (int)o0h + wr * 64 + i * 16 + quad * 4;
                    const f32x4 inv = *(const f32x4*)(bn + ob);
                    const f32x4 add = *(const f32x4*)(bn + 512 + ob);
#pragma unroll
                    for (int j = 0; j < 4; ++j) {
                        const int col = wc * 64 + j * 16 + l15;
                        const float gt = gatef[t * 128 + col];
                        u16x4 w;
#pragma unroll
                        for (int r = 0; r < 4; ++r) {
                            const float y = acc[i][j][r] * inv[r] + add[r];
                            float v = (st[i][j][r] + y) * 0.5f;
                            const float s = (v >= 1.0f) ? 1.f : 0.f;
                            st[i][j][r] = (v >= 1.0f) ? 0.f : v;
                            w[r] = (s * gt != 0.f) ? (u16)0x3F80 : (u16)0;
                        }
                        *(u16x4*)(&stg[col * 136 + wr * 64 + i * 16 + quad * 4]) = w;
                    }
                }
                __syncthreads();
                // coalesced store of the (v,d) tile
#pragma unroll
                for (int cc = 0; cc < 8; ++cc) {
                    const int c = cc * 256 + tid;
                    const int vv = c >> 4, ch = c & 15;
                    const float4 f4 = *(const float4*)(stg + (size_t)vv * 136 + ch * 8);
                    *(float4*)(ws + OUTBT
                               + ((size_t)((t * 64 + b) * 256 + v0 + vv) * 512 + o0h) * 2
                               + ch * 16) = f4;
                }
                __syncthreads();
            }
        }
    }
}

// ---------------------------------------------------------------------------
// Fused p: out2 = LIF(bn_p(Wp @ out)). BK=64 (8 iters), all 4 t in-block.
// ---------------------------------------------------------------------------
__global__ __launch_bounds__(256, 2) void k_p_fused(char* __restrict__ ws,
                                                    float* __restrict__ out2)
{
    __shared__ u16 stg[16384];    // 4t x (2kh x 4f) x 512 = 32KB

    const int tid  = threadIdx.x;
    const int lane = tid & 63;
    const int wave = tid >> 6;
    const int wr = wave >> 1, wc = wave & 1;
    const int quad = lane >> 4;
    const int l15  = lane & 15;

    const unsigned bid  = blockIdx.x;
    const unsigned rr   = bid >> 3;
    const unsigned ot   = rr & 3;
    const unsigned unit = (bid & 7) + 8u * (rr >> 2);   // 0..255
    const unsigned b    = unit >> 2;
    const unsigned vt   = unit & 3;
    const unsigned v0   = vt * 64u;
    const unsigned o0   = ot * 128u;

    const unsigned rbase = (unsigned)OUTBT + (b * 256u + v0 + (unsigned)l15) * 1024u
                         + (unsigned)(lane >> 4) * 16u;
    unsigned ab[3];
#pragma unroll
    for (int s = 0; s < 3; ++s)
        ab[s] = (unsigned)WT + (6u + (unsigned)s) * 524288u
              + ot * 131072u + (unsigned)wr * 4096u + (unsigned)lane * 16u;

    f32x4 acc[4][4][2];   // [t][i][j]
#pragma unroll
    for (int t = 0; t < 4; ++t)
#pragma unroll
        for (int i = 0; i < 4; ++i)
#pragma unroll
            for (int j = 0; j < 2; ++j) acc[t][i][j] = (f32x4){0.f, 0.f, 0.f, 0.f};

    for (int it2 = 0; it2 < 8; ++it2) {
        const unsigned ko = (unsigned)it2 * 128u;
        // stage: 32 chunks, 8 per wave
#pragma unroll
        for (int u = 0; u < 8; ++u) {
            const int fg = wave * 8 + u;       // 0..31
            const int tt = fg >> 3;
            const int rem = fg & 7;
            const int kh = rem >> 2, f = rem & 3;
            gld_lds16(ws + (size_t)(rbase + (unsigned)tt * 16777216u
                                    + (unsigned)f * 16384u + ko + (unsigned)kh * 64u),
                      stg + (size_t)(tt * 8 + kh * 4 + f) * 512);
        }
        __syncthreads();

#pragma unroll
        for (int kh = 0; kh < 2; ++kh) {
            bf16x8 bfr[4][2];
#pragma unroll
            for (int tt = 0; tt < 4; ++tt)
#pragma unroll
                for (int j = 0; j < 2; ++j)
                    bfr[tt][j] = *(const bf16x8*)(stg
                        + (size_t)(tt * 8 + kh * 4 + wc * 2 + j) * 512 + lane * 8);
#pragma unroll
            for (int i = 0; i < 4; ++i) {
                bf16x8 afr[3];
#pragma unroll
                for (int s = 0; s < 3; ++s)
                    afr[s] = *(const bf16x8*)(ws + (size_t)(ab[s]
                              + (unsigned)it2 * 16384u + (unsigned)kh * 8192u
                              + (unsigned)i * 1024u));
#pragma unroll
                for (int tt = 0; tt < 4; ++tt)
#pragma unroll
                    for (int p = 0; p < 3; ++p)
#pragma unroll
                        for (int j = 0; j < 2; ++j)
                            acc[tt][i][j] = __builtin_amdgcn_mfma_f32_16x16x32_bf16(
                                afr[p], bfr[tt][j], acc[tt][i][j], 0, 0, 0);
            }
        }
        __syncthreads();
    }

    // epilogue: BN + LIF over t, write spikes (T,B,D,V) fp32
    const float* bn = (const float*)(ws + BNOF + 8192);
#pragma unroll
    for (int i = 0; i < 4; ++i) {
        const int ob = (int)o0 + wr * 64 + i * 16 + quad * 4;
        const f32x4 inv = *(const f32x4*)(bn + ob);
        const f32x4 add = *(const f32x4*)(bn + 512 + ob);
#pragma unroll
        for (int j = 0; j < 2; ++j) {
            const int col = (int)v0 + wc * 32 + j * 16 + l15;
#pragma unroll
            for (int r = 0; r < 4; ++r) {
                float v = 0.f;
#pragma unroll
                for (int tt = 0; tt < 4; ++tt) {
                    const float y = acc[tt][i][j][r] * inv[r] + add[r];
                    v = (v + y) * 0.5f;
                    const float s = (v >= 1.0f) ? 1.f : 0.f;
                    v = (v >= 1.0f) ? 0.f : v;
                    out2[((size_t)(tt * 64 + b) * 512 + ob + r) * 256 + col] = s;
                }
            }
        }
    }
}

// ---------------------------------------------------------------------------
extern "C" void kernel_launch(void* const* d_in, const int* in_sizes, int n_in,
                              void* d_out, int out_size, void* d_ws, size_t ws_size,
                              hipStream_t stream)
{
    const float* x  = (const float*)d_in[0];
    const float* Wq = (const float*)d_in[1];
    const float* qg = (const float*)d_in[2];
    const float* qb = (const float*)d_in[3];
    const float* qm = (const float*)d_in[4];
    const float* qv = (const float*)d_in[5];
    const float* Wk = (const float*)d_in[6];
    const float* kg = (const float*)d_in[7];
    const float* kb = (const float*)d_in[8];
    const float* km = (const float*)d_in[9];
    const float* kv = (const float*)d_in[10];
    const float* Wp = (const float*)d_in[11];
    const float* pg = (const float*)d_in[12];
    const float* pb = (const float*)d_in[13];
    const float* pm = (const float*)d_in[14];
    const float* pv = (const float*)d_in[15];

    char* ws = (char*)d_ws;

    k_prep2<<<384, 256, 0, stream>>>(Wq, Wk, Wp, qg, qb, qm, qv,
                                     kg, kb, km, kv, pg, pb, pm, pv, ws);

    k_split_x<<<dim3(4, 8, 256), 256, 0, stream>>>(
        x, (u16*)(ws + XSH), (u16*)(ws + XSM), (u16*)(ws + XSL));

    k_qk_fused<<<512, 256, 0, stream>>>(ws);

    k_p_fused<<<1024, 256, 0, stream>>>(ws, (float*)d_out);
}

// Round 6
// 761.122 us; speedup vs baseline: 1.2494x; 1.2494x over previous
//
#include <hip/hip_runtime.h>

#define T_ 4
#define B_ 64
#define D_ 512
#define V_ 256

// ---- workspace byte offsets ----
// x splits, frag-linear: [bt 256][it 16][vg 16][lane 64][e 8] u16 (67.1 MB each)
#define XSH   0ull
#define XSM   67108864ull
#define XSL   134217728ull
// gate*k spikes, binary bf16, same frag-linear layout (67.1 MB)
#define OUTBT 201326592ull
// W splits frag-linear: (mat*3+s) arrays: [head 4][it 16][ip 8][lane 64][e 8]
#define WT    268435456ull
#define BNOF  273154048ull     // 6x512 floats

typedef unsigned short u16;
typedef __attribute__((ext_vector_type(8))) __bf16 bf16x8;
typedef __attribute__((ext_vector_type(4))) float f32x4;
typedef __attribute__((ext_vector_type(8))) unsigned short u16x8;
typedef __attribute__((ext_vector_type(4))) unsigned short u16x4;

__device__ __forceinline__ u16 f2bf(float f) {
    unsigned u = __float_as_uint(f);
    return (u16)((u + 0x7FFFu + ((u >> 16) & 1u)) >> 16);
}
__device__ __forceinline__ float bf2f(u16 h) {
    return __uint_as_float(((unsigned)h) << 16);
}

// ---------------------------------------------------------------------------
// prep: W 3-way bf16 splits in frag-linear layout + BN constants (unchanged).
// ---------------------------------------------------------------------------
__global__ __launch_bounds__(256) void k_prep2(
    const float* __restrict__ Wq, const float* __restrict__ Wk, const float* __restrict__ Wp,
    const float* __restrict__ qg, const float* __restrict__ qb,
    const float* __restrict__ qm, const float* __restrict__ qv,
    const float* __restrict__ kg, const float* __restrict__ kb,
    const float* __restrict__ km, const float* __restrict__ kv,
    const float* __restrict__ pg, const float* __restrict__ pb,
    const float* __restrict__ pm, const float* __restrict__ pv,
    char* __restrict__ ws)
{
    const int g = blockIdx.x * 256 + threadIdx.x;   // [0, 98304)
    const int mat = g >> 15;
    const int r = g & 32767;
    const int lane = r & 63;
    const int q = r >> 6;            // (head*16+it)*8+ip
    const int ip = q & 7;
    const int q2 = q >> 3;
    const int it = q2 & 15;
    const int head = q2 >> 4;
    const int row = head * 128 + ip * 16 + (lane & 15);
    const int kcol = it * 32 + (lane >> 4) * 8;
    const float* W = (mat == 0) ? Wq : (mat == 1 ? Wk : Wp);

    u16x8 h8, m8, l8;
#pragma unroll
    for (int e = 0; e < 8; ++e) {
        const float f = W[row * 512 + kcol + e];
        const u16 h = f2bf(f);          const float fh = bf2f(h);
        const u16 m = f2bf(f - fh);     const float fm = bf2f(m);
        const u16 l = f2bf(f - fh - fm);
        h8[e] = h; m8[e] = m; l8[e] = l;
    }
    u16* wt = (u16*)(ws + WT);
    const size_t o = (size_t)r * 8;
    *(u16x8*)(wt + (size_t)(mat * 3 + 0) * 262144 + o) = h8;
    *(u16x8*)(wt + (size_t)(mat * 3 + 1) * 262144 + o) = m8;
    *(u16x8*)(wt + (size_t)(mat * 3 + 2) * 262144 + o) = l8;

    if (g < 512) {
        float* bn = (float*)(ws + BNOF);
        float iv;
        iv = qg[g] * (1.0f / sqrtf(qv[g] + 1e-5f)); bn[g]        = iv; bn[512  + g] = qb[g] - qm[g] * iv;
        iv = kg[g] * (1.0f / sqrtf(kv[g] + 1e-5f)); bn[1024 + g] = iv; bn[1536 + g] = kb[g] - km[g] * iv;
        iv = pg[g] * (1.0f / sqrtf(pv[g] + 1e-5f)); bn[2048 + g] = iv; bn[2560 + g] = pb[g] - pm[g] * iv;
    }
}

// ---------------------------------------------------------------------------
// split_x: x (t,b,d,v) fp32 -> 3-way bf16 splits in frag-linear layout.
// Element (bt, it, vg, lane, e) = split( x[bt][it*32 + (lane>>4)*8 + e][vg*16 + (lane&15)] )
// ---------------------------------------------------------------------------
__global__ __launch_bounds__(256) void k_split_x2(
    const float* __restrict__ x, char* __restrict__ ws)
{
    const int bt = blockIdx.x >> 4;
    const int it = blockIdx.x & 15;
    const int tid = threadIdx.x;
#pragma unroll
    for (int r2 = 0; r2 < 4; ++r2) {
        const int slot = r2 * 256 + tid;       // 0..1023 = vg*64 + lane
        const int vg = slot >> 6;
        const int ll = slot & 63;
        const int v  = vg * 16 + (ll & 15);
        const int d0 = it * 32 + (ll >> 4) * 8;
        u16x8 h8, m8, l8;
#pragma unroll
        for (int e = 0; e < 8; ++e) {
            const float f = x[(size_t)bt * 131072 + (size_t)(d0 + e) * 256 + v];
            const u16 h = f2bf(f);          const float fh = bf2f(h);
            const u16 m = f2bf(f - fh);     const float fm = bf2f(m);
            const u16 lo = f2bf(f - fh - fm);
            h8[e] = h; m8[e] = m; l8[e] = lo;
        }
        const size_t o = (size_t)bt * 262144ull + (size_t)it * 16384ull
                       + (size_t)vg * 1024ull + (size_t)ll * 16ull;
        *(u16x8*)(ws + XSH + o) = h8;
        *(u16x8*)(ws + XSM + o) = m8;
        *(u16x8*)(ws + XSL + o) = l8;
    }
}

// ---------------------------------------------------------------------------
// Fused q+k, BARRIER-FREE K-loop: all frags direct from global (frag-linear,
// L2-hot). Block = (b, head): 512 threads, 8 waves (2 wr x 4 wc), wave tile
// 64o x 64v, full 256-v row per block. Barriers only in per-t epilogues.
// ---------------------------------------------------------------------------
__global__ __launch_bounds__(512, 2) void k_qk2(char* __restrict__ ws)
{
    __shared__ u16 tile[32768];      // 64KB: k-spike out tile, frag-linear
    __shared__ float qs[2][256];
    __shared__ float gatef[4][256];

    const int tid  = threadIdx.x;
    const int lane = tid & 63;
    const int wave = tid >> 6;       // 0..7
    const int wr = wave >> 2;        // 0..1  (o half)
    const int wc = wave & 3;         // 0..3  (v quarter)
    const int quad = lane >> 4;
    const int l15  = lane & 15;

    const int b    = blockIdx.x >> 2;
    const int head = blockIdx.x & 3;

    constexpr int PA[6] = {0, 0, 1, 1, 0, 2};
    constexpr int PB[6] = {0, 1, 0, 1, 2, 0};

    float gstate = 0.f;

    for (int ph = 0; ph < 2; ++ph) {
        const size_t abase = WT + (size_t)ph * 3ull * 524288ull
                           + (size_t)head * 131072ull
                           + (size_t)wr * 4096ull + (size_t)lane * 16ull;
        const float* bn = (const float*)(ws + BNOF + (size_t)ph * 4096);

        f32x4 st[4][4];
#pragma unroll
        for (int i = 0; i < 4; ++i)
#pragma unroll
            for (int j = 0; j < 4; ++j) st[i][j] = (f32x4){0.f, 0.f, 0.f, 0.f};

        for (int t = 0; t < 4; ++t) {
            const int bt = t * 64 + b;
            const size_t bbase = (size_t)bt * 262144ull
                               + (size_t)(wc * 4) * 1024ull + (size_t)lane * 16ull;
            f32x4 acc[4][4];
#pragma unroll
            for (int i = 0; i < 4; ++i)
#pragma unroll
                for (int j = 0; j < 4; ++j) acc[i][j] = (f32x4){0.f, 0.f, 0.f, 0.f};

#pragma unroll 4
            for (int it = 0; it < 16; ++it) {
                bf16x8 afr[3][4];
#pragma unroll
                for (int s = 0; s < 3; ++s)
#pragma unroll
                    for (int i = 0; i < 4; ++i)
                        afr[s][i] = *(const bf16x8*)(ws + abase + (size_t)s * 524288ull
                                      + (size_t)it * 8192ull + (size_t)i * 1024ull);
#pragma unroll
                for (int j = 0; j < 4; ++j) {
                    bf16x8 bfr[3];
#pragma unroll
                    for (int s = 0; s < 3; ++s)
                        bfr[s] = *(const bf16x8*)(ws + (size_t)s * 67108864ull + bbase
                                   + (size_t)it * 16384ull + (size_t)j * 1024ull);
#pragma unroll
                    for (int i = 0; i < 4; ++i)
#pragma unroll
                        for (int p = 0; p < 6; ++p)
                            acc[i][j] = __builtin_amdgcn_mfma_f32_16x16x32_bf16(
                                afr[PA[p]][i], bfr[PB[p]], acc[i][j], 0, 0, 0);
                }
            }

            if (ph == 0) {
                // ---- phase Q epilogue: BN + LIF + per-column spike sums ----
                float qp[4] = {0.f, 0.f, 0.f, 0.f};
#pragma unroll
                for (int i = 0; i < 4; ++i) {
                    const int ob = head * 128 + wr * 64 + i * 16 + quad * 4;
                    const f32x4 inv = *(const f32x4*)(bn + ob);
                    const f32x4 add = *(const f32x4*)(bn + 512 + ob);
#pragma unroll
                    for (int j = 0; j < 4; ++j)
#pragma unroll
                        for (int r = 0; r < 4; ++r) {
                            const float y = acc[i][j][r] * inv[r] + add[r];
                            float v = (st[i][j][r] + y) * 0.5f;
                            const float s = (v >= 1.0f) ? 1.f : 0.f;
                            st[i][j][r] = (v >= 1.0f) ? 0.f : v;
                            qp[j] += s;
                        }
                }
#pragma unroll
                for (int j = 0; j < 4; ++j) {
                    qp[j] += __shfl_xor(qp[j], 16, 64);
                    qp[j] += __shfl_xor(qp[j], 32, 64);
                }
                if (quad == 0) {
#pragma unroll
                    for (int j = 0; j < 4; ++j)
                        qs[wr][wc * 64 + j * 16 + l15] = qp[j];
                }
                __syncthreads();
                if (tid < 256) {
                    const float qsum = qs[0][tid] + qs[1][tid];
                    gstate = (gstate + qsum) * 0.5f;
                    const float gt = (gstate >= 0.5f) ? 1.f : 0.f;
                    gstate = (gstate >= 0.5f) ? 0.f : gstate;
                    gatef[t][tid] = gt;
                }
                __syncthreads();
            } else {
                // ---- phase K epilogue: BN + LIF + gate -> frag-linear tile ----
#pragma unroll
                for (int i = 0; i < 4; ++i) {
                    const int ob = head * 128 + wr * 64 + i * 16 + quad * 4;
                    const f32x4 inv = *(const f32x4*)(bn + ob);
                    const f32x4 add = *(const f32x4*)(bn + 512 + ob);
                    const int itL = wr * 2 + (i >> 1);
                    const int ls  = ((i & 1) * 2 + (quad >> 1)) * 16 + l15;
                    const int e0  = (quad & 1) * 4;
#pragma unroll
                    for (int j = 0; j < 4; ++j) {
                        const int col = wc * 64 + j * 16 + l15;
                        const float gt = gatef[t][col];
                        u16x4 w;
#pragma unroll
                        for (int r = 0; r < 4; ++r) {
                            const float y = acc[i][j][r] * inv[r] + add[r];
                            float v = (st[i][j][r] + y) * 0.5f;
                            const float s = (v >= 1.0f) ? 1.f : 0.f;
                            st[i][j][r] = (v >= 1.0f) ? 0.f : v;
                            w[r] = (s * gt != 0.f) ? (u16)0x3F80 : (u16)0;
                        }
                        *(u16x4*)&tile[(size_t)((itL * 16 + wc * 4 + j) * 64 + ls) * 8 + e0] = w;
                    }
                }
                __syncthreads();
                const size_t dst = OUTBT + ((size_t)bt * 16ull + (size_t)head * 4ull) * 16384ull;
#pragma unroll
                for (int c = 0; c < 8; ++c) {
                    const int idx = c * 512 + tid;   // float4 units, 0..4095
                    *(float4*)(ws + dst + (size_t)idx * 16) = *(const float4*)&tile[(size_t)idx * 8];
                }
                __syncthreads();
            }
        }
    }
}

// ---------------------------------------------------------------------------
// Fused p, BARRIER-FREE: out2 = LIF(bn_p(Wp @ out)). Block = (b, ot): 512
// threads, 128o x 256v, t-loop outer (LIF state in regs), B binary 1-split.
// ---------------------------------------------------------------------------
__global__ __launch_bounds__(512, 2) void k_p2(char* __restrict__ ws,
                                               float* __restrict__ out2)
{
    const int tid  = threadIdx.x;
    const int lane = tid & 63;
    const int wave = tid >> 6;
    const int wr = wave >> 2;
    const int wc = wave & 3;
    const int quad = lane >> 4;
    const int l15  = lane & 15;

    const int b  = blockIdx.x >> 2;
    const int ot = blockIdx.x & 3;

    const size_t abase = WT + 6ull * 524288ull + (size_t)ot * 131072ull
                       + (size_t)wr * 4096ull + (size_t)lane * 16ull;
    const float* bn = (const float*)(ws + BNOF + 8192);

    f32x4 st[4][4];
#pragma unroll
    for (int i = 0; i < 4; ++i)
#pragma unroll
        for (int j = 0; j < 4; ++j) st[i][j] = (f32x4){0.f, 0.f, 0.f, 0.f};

    for (int t = 0; t < 4; ++t) {
        const int bt = t * 64 + b;
        const size_t bbase = OUTBT + (size_t)bt * 262144ull
                           + (size_t)(wc * 4) * 1024ull + (size_t)lane * 16ull;
        f32x4 acc[4][4];
#pragma unroll
        for (int i = 0; i < 4; ++i)
#pragma unroll
            for (int j = 0; j < 4; ++j) acc[i][j] = (f32x4){0.f, 0.f, 0.f, 0.f};

#pragma unroll 4
        for (int it = 0; it < 16; ++it) {
            bf16x8 afr[3][4];
#pragma unroll
            for (int s = 0; s < 3; ++s)
#pragma unroll
                for (int i = 0; i < 4; ++i)
                    afr[s][i] = *(const bf16x8*)(ws + abase + (size_t)s * 524288ull
                                  + (size_t)it * 8192ull + (size_t)i * 1024ull);
#pragma unroll
            for (int j = 0; j < 4; ++j) {
                const bf16x8 bfr = *(const bf16x8*)(ws + bbase
                                     + (size_t)it * 16384ull + (size_t)j * 1024ull);
#pragma unroll
                for (int i = 0; i < 4; ++i)
#pragma unroll
                    for (int p = 0; p < 3; ++p)
                        acc[i][j] = __builtin_amdgcn_mfma_f32_16x16x32_bf16(
                            afr[p][i], bfr, acc[i][j], 0, 0, 0);
            }
        }

        // epilogue: BN + LIF step t, write spikes (T,B,D,V) fp32
#pragma unroll
        for (int i = 0; i < 4; ++i) {
            const int ob = ot * 128 + wr * 64 + i * 16 + quad * 4;
            const f32x4 inv = *(const f32x4*)(bn + ob);
            const f32x4 add = *(const f32x4*)(bn + 512 + ob);
#pragma unroll
            for (int j = 0; j < 4; ++j) {
                const int col = wc * 64 + j * 16 + l15;
#pragma unroll
                for (int r = 0; r < 4; ++r) {
                    const float y = acc[i][j][r] * inv[r] + add[r];
                    float v = (st[i][j][r] + y) * 0.5f;
                    const float s = (v >= 1.0f) ? 1.f : 0.f;
                    st[i][j][r] = (v >= 1.0f) ? 0.f : v;
                    out2[((size_t)(t * 64 + b) * 512 + ob + r) * 256 + col] = s;
                }
            }
        }
    }
}

// ---------------------------------------------------------------------------
extern "C" void kernel_launch(void* const* d_in, const int* in_sizes, int n_in,
                              void* d_out, int out_size, void* d_ws, size_t ws_size,
                              hipStream_t stream)
{
    const float* x  = (const float*)d_in[0];
    const float* Wq = (const float*)d_in[1];
    const float* qg = (const float*)d_in[2];
    const float* qb = (const float*)d_in[3];
    const float* qm = (const float*)d_in[4];
    const float* qv = (const float*)d_in[5];
    const float* Wk = (const float*)d_in[6];
    const float* kg = (const float*)d_in[7];
    const float* kb = (const float*)d_in[8];
    const float* km = (const float*)d_in[9];
    const float* kv = (const float*)d_in[10];
    const float* Wp = (const float*)d_in[11];
    const float* pg = (const float*)d_in[12];
    const float* pb = (const float*)d_in[13];
    const float* pm = (const float*)d_in[14];
    const float* pv = (const float*)d_in[15];

    char* ws = (char*)d_ws;

    k_prep2<<<384, 256, 0, stream>>>(Wq, Wk, Wp, qg, qb, qm, qv,
                                     kg, kb, km, kv, pg, pb, pm, pv, ws);

    k_split_x2<<<4096, 256, 0, stream>>>(x, ws);

    k_qk2<<<256, 512, 0, stream>>>(ws);

    k_p2<<<256, 512, 0, stream>>>(ws, (float*)d_out);
}